// Round 8
// baseline (120.691 us; speedup 1.0000x reference)
//
#include <hip/hip_runtime.h>

typedef _Float16 f16;
typedef _Float16 f16x4 __attribute__((ext_vector_type(4)));
typedef _Float16 f16x8 __attribute__((ext_vector_type(8)));
typedef float f32x4 __attribute__((ext_vector_type(4)));

#define B_TOT 16384
#define LAT_  16
#define STY_  64
#define ND_   8

#define ROWS 64            // rows per block, held in LDS through all 8 layers
#define NTHR 1024          // 16 waves (4 per SIMD)
#define NBLK 256           // B_TOT / ROWS, exactly 1 block/CU

// ---------------- prep: transpose+cast all weights into k-tiled fragment layout -
// dst elem (out-col n, k) -> dst[((k>>5)*NR + n)*32 + (k&31)]   (f16)
// z=0: W0 (16x512, Kpad=32, NR=512); z=1..3: W1..W3 (512x512, NR=512)
// z=4..11: U0; 12..19: U1; 20..27: U2 (512x512, NR=512)
// z=28..35: U3 (512x64, NR=64)
__global__ void prep_k(const float* W0, f16* Wt0, const float* W1, f16* Wt1,
                       const float* W2, f16* Wt2, const float* W3, f16* Wt3,
                       const float* U0, f16* U0t, const float* U1, f16* U1t,
                       const float* U2, f16* U2t, const float* U3, f16* U3t) {
  int z = blockIdx.z;
  const float* src; f16* dst; int Kin, Nin, Kpad, NR;
  if (z == 0)      { src = W0; dst = Wt0; Kin = 16;  Nin = 512; Kpad = 32;  NR = 512; }
  else if (z == 1) { src = W1; dst = Wt1; Kin = 512; Nin = 512; Kpad = 512; NR = 512; }
  else if (z == 2) { src = W2; dst = Wt2; Kin = 512; Nin = 512; Kpad = 512; NR = 512; }
  else if (z == 3) { src = W3; dst = Wt3; Kin = 512; Nin = 512; Kpad = 512; NR = 512; }
  else if (z < 12) { int d = z - 4;  src = U0 + (long)d * 262144; dst = U0t + (long)d * 262144; Kin = 512; Nin = 512; Kpad = 512; NR = 512; }
  else if (z < 20) { int d = z - 12; src = U1 + (long)d * 262144; dst = U1t + (long)d * 262144; Kin = 512; Nin = 512; Kpad = 512; NR = 512; }
  else if (z < 28) { int d = z - 20; src = U2 + (long)d * 262144; dst = U2t + (long)d * 262144; Kin = 512; Nin = 512; Kpad = 512; NR = 512; }
  else             { int d = z - 28; src = U3 + (long)d * 32768;  dst = U3t + (long)d * 32768;  Kin = 512; Nin = 64;  Kpad = 512; NR = 64; }

  __shared__ float tile[32][33];
  int k0 = blockIdx.y * 32, n0 = blockIdx.x * 32;
  int tx = threadIdx.x, ty = threadIdx.y;  // 32 x 8
  #pragma unroll
  for (int i = 0; i < 32; i += 8) {
    int k = k0 + ty + i, n = n0 + tx;
    tile[ty + i][tx] = (k < Kin && n < Nin) ? src[(long)k * Nin + n] : 0.f;
  }
  __syncthreads();
  #pragma unroll
  for (int i = 0; i < 32; i += 8) {
    int n = n0 + ty + i, k = k0 + tx;
    if (n < NR && k < Kpad)
      dst[(long)(((k >> 5) * NR + n) << 5) | (k & 31)] = (f16)tile[tx][ty + i];
  }
}

// ---------------- bucketing (atomics-free, deterministic) ----------------
#define NT_BUCKET 1024
#define RPT 16

__global__ __launch_bounds__(NT_BUCKET) void bucket_k(const int* __restrict__ y,
                                                      int* __restrict__ offsets,
                                                      int* __restrict__ perm) {
  __shared__ int hist[ND_][NT_BUCKET];
  __shared__ int totals[ND_];
  __shared__ int bases[ND_ + 1];
  int t = threadIdx.x;
  int base = t * RPT;

  #pragma unroll
  for (int d = 0; d < ND_; d++) hist[d][t] = 0;
  int yv[RPT];
  #pragma unroll
  for (int i = 0; i < RPT; i++) {
    yv[i] = y[base + i];
    hist[yv[i]][t]++;
  }
  __syncthreads();

  int wave = t >> 6, lane = t & 63;
  if (wave < ND_) {
    int d = wave;
    int carry = 0;
    for (int c = 0; c < NT_BUCKET; c += 64) {
      int v = hist[d][c + lane];
      int s = v;
      #pragma unroll
      for (int off = 1; off < 64; off <<= 1) {
        int u = __shfl_up(s, off, 64);
        if (lane >= off) s += u;
      }
      hist[d][c + lane] = carry + s - v;   // exclusive prefix
      carry += __shfl(s, 63, 64);
    }
    if (lane == 0) totals[d] = carry;
  }
  __syncthreads();

  if (t == 0) {
    int s = 0;
    #pragma unroll
    for (int d = 0; d < ND_; d++) { bases[d] = s; offsets[d] = s; s += totals[d]; }
    bases[ND_] = s; offsets[ND_] = s;
  }
  __syncthreads();

  #pragma unroll
  for (int i = 0; i < RPT; i++) {
    int d = yv[i];
    int pos = bases[d] + hist[d][t];
    hist[d][t]++;
    perm[pos] = base + i;
  }
}

#define MFMA_(b, a, c) __builtin_amdgcn_mfma_f32_16x16x32_f16((b), (a), (c), 0, 0, 0)

// ---------------- fused layer ----------------
// act layout: f16 [16 kt][64 row][32 col] (64 KB). An af fragment read (fixed m,kt)
// = wave's 64 lanes tiling a contiguous 1KB -> conflict-free ds_read_b128.
// Weights k-tiled [KT][NR][32]; bf fragments loaded global->VGPR (contiguous 1KB/wave).
// Swapped mfma(bf, af): lane holds act-row (m*16+lane&15), out-cols wn+n*16+(lane>>4)*4+j.
// 16 waves: wave wid owns out-cols wn=wid*32 (NF=2, MF=4). No barriers in K-loop.
template<int KT, bool FINAL>
__device__ __forceinline__ void do_layer(
    const f16* __restrict__ Wk, const float* __restrict__ bias,
    f16* __restrict__ act, int rlo, int rhi,
    const int* __restrict__ perm, int slot0, float* __restrict__ out, int t) {
  const int lane = t & 63, wid = t >> 6;
  const int lr = lane & 15, lg = lane >> 4;
  char* actb = (char*)act;

  __syncthreads();                       // previous layer's act writes visible

  if (!FINAL) {
    const int wn = wid * 32;
    const f16* wp0 = Wk + ((wn + lr) * 32 + lg * 8);
    const f16* wp1 = Wk + ((wn + 16 + lr) * 32 + lg * 8);
    const char* ab[4];
    #pragma unroll
    for (int m = 0; m < 4; m++)
      ab[m] = actb + (m * 16 + lr) * 64 + lg * 16;   // + kt*4096 imm offset

    f32x4 acc[4][2];
    #pragma unroll
    for (int m = 0; m < 4; m++) {
      acc[m][0] = f32x4{0.f, 0.f, 0.f, 0.f};
      acc[m][1] = f32x4{0.f, 0.f, 0.f, 0.f};
    }

    f16x8 a0[4], a1[4], b00, b01, b10, b11;
    b00 = *(const f16x8*)wp0;
    b01 = *(const f16x8*)wp1;
    #pragma unroll
    for (int m = 0; m < 4; m++) a0[m] = *(const f16x8*)(ab[m]);

    if constexpr (KT == 1) {
      #pragma unroll
      for (int m = 0; m < 4; m++) {
        acc[m][0] = MFMA_(b00, a0[m], acc[m][0]);
        acc[m][1] = MFMA_(b01, a0[m], acc[m][1]);
      }
    } else {
      #pragma unroll
      for (int kt2 = 0; kt2 < KT / 2; kt2++) {
        const int k1 = 2 * kt2 + 1, k2 = 2 * kt2 + 2;
        // prefetch set1 (k1) before consuming set0
        b10 = *(const f16x8*)(wp0 + k1 * 16384);
        b11 = *(const f16x8*)(wp1 + k1 * 16384);
        #pragma unroll
        for (int m = 0; m < 4; m++) a1[m] = *(const f16x8*)(ab[m] + k1 * 4096);
        #pragma unroll
        for (int m = 0; m < 4; m++) {
          acc[m][0] = MFMA_(b00, a0[m], acc[m][0]);
          acc[m][1] = MFMA_(b01, a0[m], acc[m][1]);
        }
        if (kt2 < KT / 2 - 1) {          // prefetch set0 (k2)
          b00 = *(const f16x8*)(wp0 + k2 * 16384);
          b01 = *(const f16x8*)(wp1 + k2 * 16384);
          #pragma unroll
          for (int m = 0; m < 4; m++) a0[m] = *(const f16x8*)(ab[m] + k2 * 4096);
        }
        #pragma unroll
        for (int m = 0; m < 4; m++) {
          acc[m][0] = MFMA_(b10, a1[m], acc[m][0]);
          acc[m][1] = MFMA_(b11, a1[m], acc[m][1]);
        }
      }
    }

    __syncthreads();                     // all af reads done before overwrite

    // epilogue: lane's act-row r = m*16+lr, out-cols cn0 = wn + n*16 + lg*4 (+j)
    // new-layout write: slab (cn0>>5) == wid; byte = wid*4096 + r*64 + (cn0&31)*2
    #pragma unroll
    for (int m = 0; m < 4; m++) {
      int r = m * 16 + lr;
      bool ok = (r >= rlo) && (r < rhi);
      #pragma unroll
      for (int n = 0; n < 2; n++) {
        int cl = n * 16 + lg * 4;        // col within slab
        f32x4 bb = *(const f32x4*)(bias + wn + cl);
        f16x4 h;
        #pragma unroll
        for (int j = 0; j < 4; j++)
          h[j] = (f16)fmaxf(acc[m][n][j] + bb[j], 0.f);
        if (ok)
          *(f16x4*)(actb + wid * 4096 + r * 64 + cl * 2) = h;
      }
    }
  } else {
    // final 512->64: wave wid -> m-frag mf=wid>>2 (rows mf*16+lr), n-frag nf=wid&3
    const int mf = wid >> 2, nf = wid & 3;
    const f16* wp = Wk + ((nf * 16 + lr) * 32 + lg * 8);   // [kt][64][32], stride 2048
    const char* abf = actb + (mf * 16 + lr) * 64 + lg * 16;
    f32x4 a = f32x4{0.f, 0.f, 0.f, 0.f};
    #pragma unroll
    for (int kt = 0; kt < 16; kt++) {
      f16x8 bf = *(const f16x8*)(wp + kt * 2048);
      f16x8 af = *(const f16x8*)(abf + kt * 4096);
      a = MFMA_(bf, af, a);
    }
    int r = mf * 16 + lr;
    if (r >= rlo && r < rhi) {
      int orig = perm[slot0 + r];
      int cn0 = nf * 16 + lg * 4;
      f32x4 bb = *(const f32x4*)(bias + cn0);
      f32x4 v;
      #pragma unroll
      for (int j = 0; j < 4; j++) v[j] = a[j] + bb[j];
      *(f32x4*)(out + (long)orig * STY_ + cn0) = v;
    }
  }
}

// ---------------- fused network kernel ----------------
__global__ __launch_bounds__(NTHR, 4) void fused_k(
    const float* __restrict__ x,
    const f16* __restrict__ Wt0, const float* __restrict__ b0,
    const f16* __restrict__ Wt1, const float* __restrict__ b1,
    const f16* __restrict__ Wt2, const float* __restrict__ b2,
    const f16* __restrict__ Wt3, const float* __restrict__ b3,
    const f16* __restrict__ U0t, const float* __restrict__ c0,
    const f16* __restrict__ U1t, const float* __restrict__ c1,
    const f16* __restrict__ U2t, const float* __restrict__ c2,
    const f16* __restrict__ U3t, const float* __restrict__ c3,
    const int* __restrict__ offs, const int* __restrict__ perm,
    float* __restrict__ out) {
  __shared__ f16 act[16 * 64 * 32];        // [kt][row][col], 64 KB

  int t = threadIdx.x;
  // XCD-chunked bijective swizzle (nwg=256, 8 XCDs)
  int wg = (blockIdx.x & 7) * (NBLK / 8) + (blockIdx.x >> 3);
  int slot0 = wg * ROWS;

  // gather x rows via perm into act slab 0 (cols 16..31 zero)
  char* actb = (char*)act;
  #pragma unroll
  for (int i = 0; i < 2; i++) {
    int e = i * NTHR + t;                  // 0..2047
    int r = e >> 5, c = e & 31;
    int orig = perm[slot0 + r];
    f16 v = (c < LAT_) ? (f16)x[orig * LAT_ + c] : (f16)0.f;
    *(f16*)(actb + r * 64 + c * 2) = v;
  }
  // (do_layer's entry __syncthreads orders these before the first af read)

  // domain span of this block's 64 consecutive slots
  int d0 = 0, d1 = 0;
  #pragma unroll
  for (int d = 1; d < ND_; d++) {
    d0 += (slot0 >= offs[d]);
    d1 += (slot0 + ROWS - 1 >= offs[d]);
  }

  // trunk (shared weights, full row range)
  do_layer<1,  false>(Wt0, b0, act, 0, ROWS, perm, slot0, out, t);
  do_layer<16, false>(Wt1, b1, act, 0, ROWS, perm, slot0, out, t);
  do_layer<16, false>(Wt2, b2, act, 0, ROWS, perm, slot0, out, t);
  do_layer<16, false>(Wt3, b3, act, 0, ROWS, perm, slot0, out, t);

  // experts: boundary blocks (d0<d1) run each layer once per domain, row-masked
  #pragma unroll 1
  for (int d = d0; d <= d1; d++) {
    int rlo = (d == d0) ? 0 : (offs[d] - slot0);
    int rhi = (d == d1) ? ROWS : (offs[d + 1] - slot0);
    do_layer<16, false>(U0t + (long)d * 262144, c0 + d * 512,
                        act, rlo, rhi, perm, slot0, out, t);
  }
  #pragma unroll 1
  for (int d = d0; d <= d1; d++) {
    int rlo = (d == d0) ? 0 : (offs[d] - slot0);
    int rhi = (d == d1) ? ROWS : (offs[d + 1] - slot0);
    do_layer<16, false>(U1t + (long)d * 262144, c1 + d * 512,
                        act, rlo, rhi, perm, slot0, out, t);
  }
  #pragma unroll 1
  for (int d = d0; d <= d1; d++) {
    int rlo = (d == d0) ? 0 : (offs[d] - slot0);
    int rhi = (d == d1) ? ROWS : (offs[d + 1] - slot0);
    do_layer<16, false>(U2t + (long)d * 262144, c2 + d * 512,
                        act, rlo, rhi, perm, slot0, out, t);
  }
  #pragma unroll 1
  for (int d = d0; d <= d1; d++) {
    int rlo = (d == d0) ? 0 : (offs[d] - slot0);
    int rhi = (d == d1) ? ROWS : (offs[d + 1] - slot0);
    do_layer<16, true>(U3t + (long)d * 32768, c3 + d * 64,
                       act, rlo, rhi, perm, slot0, out, t);
  }
}

// ---------------- launch ----------------

extern "C" void kernel_launch(void* const* d_in, const int* in_sizes, int n_in,
                              void* d_out, int out_size, void* d_ws, size_t ws_size,
                              hipStream_t stream) {
  const float* x  = (const float*)d_in[0];
  const int*   y  = (const int*)  d_in[1];
  const float* W0 = (const float*)d_in[2];
  const float* b0 = (const float*)d_in[3];
  const float* W1 = (const float*)d_in[4];
  const float* b1 = (const float*)d_in[5];
  const float* W2 = (const float*)d_in[6];
  const float* b2 = (const float*)d_in[7];
  const float* W3 = (const float*)d_in[8];
  const float* b3 = (const float*)d_in[9];
  const float* U0 = (const float*)d_in[10];
  const float* c0 = (const float*)d_in[11];
  const float* U1 = (const float*)d_in[12];
  const float* c1 = (const float*)d_in[13];
  const float* U2 = (const float*)d_in[14];
  const float* c2 = (const float*)d_in[15];
  const float* U3 = (const float*)d_in[16];
  const float* c3 = (const float*)d_in[17];
  float* out = (float*)d_out;

  char* p = (char*)d_ws;
  auto alloc = [&](size_t bytes) -> char* {
    char* r = p; p += (bytes + 255) & ~(size_t)255; return r;
  };
  f16* Wt0 = (f16*)alloc((size_t)512 * 32 * 2);
  f16* Wt1 = (f16*)alloc((size_t)512 * 512 * 2);
  f16* Wt2 = (f16*)alloc((size_t)512 * 512 * 2);
  f16* Wt3 = (f16*)alloc((size_t)512 * 512 * 2);
  f16* U0t = (f16*)alloc((size_t)ND_ * 512 * 512 * 2);
  f16* U1t = (f16*)alloc((size_t)ND_ * 512 * 512 * 2);
  f16* U2t = (f16*)alloc((size_t)ND_ * 512 * 512 * 2);
  f16* U3t = (f16*)alloc((size_t)ND_ * 16 * 64 * 32 * 2);
  int* offsets = (int*)alloc((ND_ + 1) * 4);
  int* perm    = (int*)alloc((size_t)B_TOT * 4);

  prep_k<<<dim3(16, 16, 36), dim3(32, 8), 0, stream>>>(W0, Wt0, W1, Wt1, W2, Wt2, W3, Wt3,
                                                       U0, U0t, U1, U1t, U2, U2t, U3, U3t);
  bucket_k<<<1, NT_BUCKET, 0, stream>>>(y, offsets, perm);
  fused_k<<<NBLK, NTHR, 0, stream>>>(x, Wt0, b0, Wt1, b1, Wt2, b2, Wt3, b3,
                                     U0t, c0, U1t, c1, U2t, c2, U3t, c3,
                                     offsets, perm, out);
}

// Round 9
// 114.018 us; speedup vs baseline: 1.0585x; 1.0585x over previous
//
#include <hip/hip_runtime.h>

typedef _Float16 f16;
typedef _Float16 f16x4 __attribute__((ext_vector_type(4)));
typedef _Float16 f16x8 __attribute__((ext_vector_type(8)));
typedef float f32x4 __attribute__((ext_vector_type(4)));

#define B_TOT 16384
#define LAT_  16
#define STY_  64
#define ND_   8

#define ROWS 64            // rows per block, held in LDS through all 8 layers
#define NTHR 1024          // 16 waves (4 per SIMD)
#define NBLK 256           // B_TOT / ROWS, exactly 1 block/CU

// act LDS geometry: f16 [16 kt][64 row][RSTR], RSTR=40 f16 (80 B) row stride.
// 80B stride => 8-lane b128 batches hit bank starts (20*lr+4*lg)%32 = all-distinct
// => conflict-free ds_read_b128 / ds_write_b64 (the 64B stride was 4x conflicted).
#define RSTR 40
#define SLAB (64 * RSTR)   // f16 per kt-slab (2560); 5120 B
#define ACT_LDS (16 * SLAB)

// ---------------- prep: transpose+cast all weights into k-tiled fragment layout -
// dst elem (out-col n, k) -> dst[((k>>5)*NR + n)*32 + (k&31)]   (f16)
// z=0: W0 (16x512, Kpad=32, NR=512); z=1..3: W1..W3 (512x512, NR=512)
// z=4..11: U0; 12..19: U1; 20..27: U2 (512x512, NR=512)
// z=28..35: U3 (512x64, NR=64)
__global__ void prep_k(const float* W0, f16* Wt0, const float* W1, f16* Wt1,
                       const float* W2, f16* Wt2, const float* W3, f16* Wt3,
                       const float* U0, f16* U0t, const float* U1, f16* U1t,
                       const float* U2, f16* U2t, const float* U3, f16* U3t) {
  int z = blockIdx.z;
  const float* src; f16* dst; int Kin, Nin, Kpad, NR;
  if (z == 0)      { src = W0; dst = Wt0; Kin = 16;  Nin = 512; Kpad = 32;  NR = 512; }
  else if (z == 1) { src = W1; dst = Wt1; Kin = 512; Nin = 512; Kpad = 512; NR = 512; }
  else if (z == 2) { src = W2; dst = Wt2; Kin = 512; Nin = 512; Kpad = 512; NR = 512; }
  else if (z == 3) { src = W3; dst = Wt3; Kin = 512; Nin = 512; Kpad = 512; NR = 512; }
  else if (z < 12) { int d = z - 4;  src = U0 + (long)d * 262144; dst = U0t + (long)d * 262144; Kin = 512; Nin = 512; Kpad = 512; NR = 512; }
  else if (z < 20) { int d = z - 12; src = U1 + (long)d * 262144; dst = U1t + (long)d * 262144; Kin = 512; Nin = 512; Kpad = 512; NR = 512; }
  else if (z < 28) { int d = z - 20; src = U2 + (long)d * 262144; dst = U2t + (long)d * 262144; Kin = 512; Nin = 512; Kpad = 512; NR = 512; }
  else             { int d = z - 28; src = U3 + (long)d * 32768;  dst = U3t + (long)d * 32768;  Kin = 512; Nin = 64;  Kpad = 512; NR = 64; }

  __shared__ float tile[32][33];
  int k0 = blockIdx.y * 32, n0 = blockIdx.x * 32;
  int tx = threadIdx.x, ty = threadIdx.y;  // 32 x 8
  #pragma unroll
  for (int i = 0; i < 32; i += 8) {
    int k = k0 + ty + i, n = n0 + tx;
    tile[ty + i][tx] = (k < Kin && n < Nin) ? src[(long)k * Nin + n] : 0.f;
  }
  __syncthreads();
  #pragma unroll
  for (int i = 0; i < 32; i += 8) {
    int n = n0 + ty + i, k = k0 + tx;
    if (n < NR && k < Kpad)
      dst[(long)(((k >> 5) * NR + n) << 5) | (k & 31)] = (f16)tile[tx][ty + i];
  }
}

// ---------------- bucketing (atomics-free, deterministic) ----------------
#define NT_BUCKET 1024
#define RPT 16

__global__ __launch_bounds__(NT_BUCKET) void bucket_k(const int* __restrict__ y,
                                                      int* __restrict__ offsets,
                                                      int* __restrict__ perm) {
  __shared__ int hist[ND_][NT_BUCKET];
  __shared__ int totals[ND_];
  __shared__ int bases[ND_ + 1];
  int t = threadIdx.x;
  int base = t * RPT;

  #pragma unroll
  for (int d = 0; d < ND_; d++) hist[d][t] = 0;
  int yv[RPT];
  #pragma unroll
  for (int i = 0; i < RPT; i++) {
    yv[i] = y[base + i];
    hist[yv[i]][t]++;
  }
  __syncthreads();

  int wave = t >> 6, lane = t & 63;
  if (wave < ND_) {
    int d = wave;
    int carry = 0;
    for (int c = 0; c < NT_BUCKET; c += 64) {
      int v = hist[d][c + lane];
      int s = v;
      #pragma unroll
      for (int off = 1; off < 64; off <<= 1) {
        int u = __shfl_up(s, off, 64);
        if (lane >= off) s += u;
      }
      hist[d][c + lane] = carry + s - v;   // exclusive prefix
      carry += __shfl(s, 63, 64);
    }
    if (lane == 0) totals[d] = carry;
  }
  __syncthreads();

  if (t == 0) {
    int s = 0;
    #pragma unroll
    for (int d = 0; d < ND_; d++) { bases[d] = s; offsets[d] = s; s += totals[d]; }
    bases[ND_] = s; offsets[ND_] = s;
  }
  __syncthreads();

  #pragma unroll
  for (int i = 0; i < RPT; i++) {
    int d = yv[i];
    int pos = bases[d] + hist[d][t];
    hist[d][t]++;
    perm[pos] = base + i;
  }
}

#define MFMA_(b, a, c) __builtin_amdgcn_mfma_f32_16x16x32_f16((b), (a), (c), 0, 0, 0)

// ---------------- fused layer ----------------
// Weights k-tiled [KT][NR][32]; bf fragments loaded global->VGPR (contiguous 1KB/wave).
// Swapped mfma(bf, af): lane holds act-row (m*16+lane&15), out-cols wn+n*16+(lane>>4)*4+j.
// 16 waves: wave wid owns out-cols wn=wid*32 (NF=2, MF=4). No barriers in K-loop.
template<int KT, bool FINAL>
__device__ __forceinline__ void do_layer(
    const f16* __restrict__ Wk, const float* __restrict__ bias,
    f16* __restrict__ act, int rlo, int rhi,
    const int* __restrict__ perm, int slot0, float* __restrict__ out, int t) {
  const int lane = t & 63, wid = t >> 6;
  const int lr = lane & 15, lg = lane >> 4;
  char* actb = (char*)act;

  __syncthreads();                       // previous layer's act writes visible

  if (!FINAL) {
    const int wn = wid * 32;
    const f16* wp0 = Wk + ((wn + lr) * 32 + lg * 8);
    const f16* wp1 = Wk + ((wn + 16 + lr) * 32 + lg * 8);
    const char* ab[4];
    #pragma unroll
    for (int m = 0; m < 4; m++)
      ab[m] = actb + (m * 16 + lr) * 80 + lg * 16;   // + kt*5120 imm offset

    f32x4 acc[4][2];
    #pragma unroll
    for (int m = 0; m < 4; m++) {
      acc[m][0] = f32x4{0.f, 0.f, 0.f, 0.f};
      acc[m][1] = f32x4{0.f, 0.f, 0.f, 0.f};
    }

    f16x8 a0[4], a1[4], b00, b01, b10, b11;
    b00 = *(const f16x8*)wp0;
    b01 = *(const f16x8*)wp1;
    #pragma unroll
    for (int m = 0; m < 4; m++) a0[m] = *(const f16x8*)(ab[m]);

    if constexpr (KT == 1) {
      #pragma unroll
      for (int m = 0; m < 4; m++) {
        acc[m][0] = MFMA_(b00, a0[m], acc[m][0]);
        acc[m][1] = MFMA_(b01, a0[m], acc[m][1]);
      }
    } else {
      #pragma unroll
      for (int kt2 = 0; kt2 < KT / 2; kt2++) {
        const int k1 = 2 * kt2 + 1, k2 = 2 * kt2 + 2;
        // prefetch set1 (k1) before consuming set0
        b10 = *(const f16x8*)(wp0 + k1 * 16384);
        b11 = *(const f16x8*)(wp1 + k1 * 16384);
        #pragma unroll
        for (int m = 0; m < 4; m++) a1[m] = *(const f16x8*)(ab[m] + k1 * 5120);
        #pragma unroll
        for (int m = 0; m < 4; m++) {
          acc[m][0] = MFMA_(b00, a0[m], acc[m][0]);
          acc[m][1] = MFMA_(b01, a0[m], acc[m][1]);
        }
        if (kt2 < KT / 2 - 1) {          // prefetch set0 (k2)
          b00 = *(const f16x8*)(wp0 + k2 * 16384);
          b01 = *(const f16x8*)(wp1 + k2 * 16384);
          #pragma unroll
          for (int m = 0; m < 4; m++) a0[m] = *(const f16x8*)(ab[m] + k2 * 5120);
        }
        #pragma unroll
        for (int m = 0; m < 4; m++) {
          acc[m][0] = MFMA_(b10, a1[m], acc[m][0]);
          acc[m][1] = MFMA_(b11, a1[m], acc[m][1]);
        }
      }
    }

    __syncthreads();                     // all af reads done before overwrite

    // epilogue: lane's act-row r = m*16+lr, out-cols cn0 = wn + n*16 + lg*4 (+j)
    // write slab (cn0>>5) == wid; byte = wid*5120 + r*80 + (cn0&31)*2
    #pragma unroll
    for (int m = 0; m < 4; m++) {
      int r = m * 16 + lr;
      bool ok = (r >= rlo) && (r < rhi);
      #pragma unroll
      for (int n = 0; n < 2; n++) {
        int cl = n * 16 + lg * 4;        // col within slab
        f32x4 bb = *(const f32x4*)(bias + wn + cl);
        f16x4 h;
        #pragma unroll
        for (int j = 0; j < 4; j++)
          h[j] = (f16)fmaxf(acc[m][n][j] + bb[j], 0.f);
        if (ok)
          *(f16x4*)(actb + wid * 5120 + r * 80 + cl * 2) = h;
      }
    }
  } else {
    // final 512->64: wave wid -> m-frag mf=wid>>2 (rows mf*16+lr), n-frag nf=wid&3
    const int mf = wid >> 2, nf = wid & 3;
    const f16* wp = Wk + ((nf * 16 + lr) * 32 + lg * 8);   // [kt][64][32], stride 2048
    const char* abf = actb + (mf * 16 + lr) * 80 + lg * 16;
    f32x4 a = f32x4{0.f, 0.f, 0.f, 0.f};
    #pragma unroll
    for (int kt = 0; kt < 16; kt++) {
      f16x8 bf = *(const f16x8*)(wp + kt * 2048);
      f16x8 af = *(const f16x8*)(abf + kt * 5120);
      a = MFMA_(bf, af, a);
    }
    int r = mf * 16 + lr;
    if (r >= rlo && r < rhi) {
      int orig = perm[slot0 + r];
      int cn0 = nf * 16 + lg * 4;
      f32x4 bb = *(const f32x4*)(bias + cn0);
      f32x4 v;
      #pragma unroll
      for (int j = 0; j < 4; j++) v[j] = a[j] + bb[j];
      *(f32x4*)(out + (long)orig * STY_ + cn0) = v;
    }
  }
}

// ---------------- fused network kernel ----------------
__global__ __launch_bounds__(NTHR, 4) void fused_k(
    const float* __restrict__ x,
    const f16* __restrict__ Wt0, const float* __restrict__ b0,
    const f16* __restrict__ Wt1, const float* __restrict__ b1,
    const f16* __restrict__ Wt2, const float* __restrict__ b2,
    const f16* __restrict__ Wt3, const float* __restrict__ b3,
    const f16* __restrict__ U0t, const float* __restrict__ c0,
    const f16* __restrict__ U1t, const float* __restrict__ c1,
    const f16* __restrict__ U2t, const float* __restrict__ c2,
    const f16* __restrict__ U3t, const float* __restrict__ c3,
    const int* __restrict__ offs, const int* __restrict__ perm,
    float* __restrict__ out) {
  __shared__ f16 act[ACT_LDS];             // [kt][row][40], 80 KB

  int t = threadIdx.x;
  // XCD-chunked bijective swizzle (nwg=256, 8 XCDs)
  int wg = (blockIdx.x & 7) * (NBLK / 8) + (blockIdx.x >> 3);
  int slot0 = wg * ROWS;

  // gather x rows via perm into act slab 0 (cols 16..31 zero)
  char* actb = (char*)act;
  #pragma unroll
  for (int i = 0; i < 2; i++) {
    int e = i * NTHR + t;                  // 0..2047
    int r = e >> 5, c = e & 31;
    int orig = perm[slot0 + r];
    f16 v = (c < LAT_) ? (f16)x[orig * LAT_ + c] : (f16)0.f;
    *(f16*)(actb + r * 80 + c * 2) = v;
  }
  // (do_layer's entry __syncthreads orders these before the first af read)

  // domain span of this block's 64 consecutive slots
  int d0 = 0, d1 = 0;
  #pragma unroll
  for (int d = 1; d < ND_; d++) {
    d0 += (slot0 >= offs[d]);
    d1 += (slot0 + ROWS - 1 >= offs[d]);
  }

  // trunk (shared weights, full row range)
  do_layer<1,  false>(Wt0, b0, act, 0, ROWS, perm, slot0, out, t);
  do_layer<16, false>(Wt1, b1, act, 0, ROWS, perm, slot0, out, t);
  do_layer<16, false>(Wt2, b2, act, 0, ROWS, perm, slot0, out, t);
  do_layer<16, false>(Wt3, b3, act, 0, ROWS, perm, slot0, out, t);

  // experts: boundary blocks (d0<d1) run each layer once per domain, row-masked
  #pragma unroll 1
  for (int d = d0; d <= d1; d++) {
    int rlo = (d == d0) ? 0 : (offs[d] - slot0);
    int rhi = (d == d1) ? ROWS : (offs[d + 1] - slot0);
    do_layer<16, false>(U0t + (long)d * 262144, c0 + d * 512,
                        act, rlo, rhi, perm, slot0, out, t);
  }
  #pragma unroll 1
  for (int d = d0; d <= d1; d++) {
    int rlo = (d == d0) ? 0 : (offs[d] - slot0);
    int rhi = (d == d1) ? ROWS : (offs[d + 1] - slot0);
    do_layer<16, false>(U1t + (long)d * 262144, c1 + d * 512,
                        act, rlo, rhi, perm, slot0, out, t);
  }
  #pragma unroll 1
  for (int d = d0; d <= d1; d++) {
    int rlo = (d == d0) ? 0 : (offs[d] - slot0);
    int rhi = (d == d1) ? ROWS : (offs[d + 1] - slot0);
    do_layer<16, false>(U2t + (long)d * 262144, c2 + d * 512,
                        act, rlo, rhi, perm, slot0, out, t);
  }
  #pragma unroll 1
  for (int d = d0; d <= d1; d++) {
    int rlo = (d == d0) ? 0 : (offs[d] - slot0);
    int rhi = (d == d1) ? ROWS : (offs[d + 1] - slot0);
    do_layer<16, true>(U3t + (long)d * 32768, c3 + d * 64,
                       act, rlo, rhi, perm, slot0, out, t);
  }
}

// ---------------- launch ----------------

extern "C" void kernel_launch(void* const* d_in, const int* in_sizes, int n_in,
                              void* d_out, int out_size, void* d_ws, size_t ws_size,
                              hipStream_t stream) {
  const float* x  = (const float*)d_in[0];
  const int*   y  = (const int*)  d_in[1];
  const float* W0 = (const float*)d_in[2];
  const float* b0 = (const float*)d_in[3];
  const float* W1 = (const float*)d_in[4];
  const float* b1 = (const float*)d_in[5];
  const float* W2 = (const float*)d_in[6];
  const float* b2 = (const float*)d_in[7];
  const float* W3 = (const float*)d_in[8];
  const float* b3 = (const float*)d_in[9];
  const float* U0 = (const float*)d_in[10];
  const float* c0 = (const float*)d_in[11];
  const float* U1 = (const float*)d_in[12];
  const float* c1 = (const float*)d_in[13];
  const float* U2 = (const float*)d_in[14];
  const float* c2 = (const float*)d_in[15];
  const float* U3 = (const float*)d_in[16];
  const float* c3 = (const float*)d_in[17];
  float* out = (float*)d_out;

  char* p = (char*)d_ws;
  auto alloc = [&](size_t bytes) -> char* {
    char* r = p; p += (bytes + 255) & ~(size_t)255; return r;
  };
  f16* Wt0 = (f16*)alloc((size_t)512 * 32 * 2);
  f16* Wt1 = (f16*)alloc((size_t)512 * 512 * 2);
  f16* Wt2 = (f16*)alloc((size_t)512 * 512 * 2);
  f16* Wt3 = (f16*)alloc((size_t)512 * 512 * 2);
  f16* U0t = (f16*)alloc((size_t)ND_ * 512 * 512 * 2);
  f16* U1t = (f16*)alloc((size_t)ND_ * 512 * 512 * 2);
  f16* U2t = (f16*)alloc((size_t)ND_ * 512 * 512 * 2);
  f16* U3t = (f16*)alloc((size_t)ND_ * 16 * 64 * 32 * 2);
  int* offsets = (int*)alloc((ND_ + 1) * 4);
  int* perm    = (int*)alloc((size_t)B_TOT * 4);

  prep_k<<<dim3(16, 16, 36), dim3(32, 8), 0, stream>>>(W0, Wt0, W1, Wt1, W2, Wt2, W3, Wt3,
                                                       U0, U0t, U1, U1t, U2, U2t, U3, U3t);
  bucket_k<<<1, NT_BUCKET, 0, stream>>>(y, offsets, perm);
  fused_k<<<NBLK, NTHR, 0, stream>>>(x, Wt0, b0, Wt1, b1, Wt2, b2, Wt3, b3,
                                     U0t, c0, U1t, c1, U2t, c2, U3t, c3,
                                     offsets, perm, out);
}